// Round 2
// baseline (7326.061 us; speedup 1.0000x reference)
//
#include <hip/hip_runtime.h>

// Problem constants
#define SEQ   512
#define BATCH 64
#define DIN   1024
#define DH    1024

typedef unsigned short u16;
typedef unsigned int   u32;
typedef __attribute__((ext_vector_type(8))) short  short8;   // 8 x bf16 MFMA operand
typedef __attribute__((ext_vector_type(4))) short  short4v;
typedef __attribute__((ext_vector_type(4))) float  floatx4;  // MFMA accumulator
typedef __attribute__((ext_vector_type(2))) unsigned int uint2v;

static __device__ __forceinline__ u16 f2bf(float f) {
    union { float f; unsigned u; } v; v.f = f;
    unsigned r = v.u + 0x7fffu + ((v.u >> 16) & 1u);   // RNE
    return (u16)(r >> 16);
}
static __device__ __forceinline__ float bf2f(u16 x) {
    union { u32 u; float f; } v; v.u = ((u32)x) << 16; return v.f;
}
static __device__ __forceinline__ float sigmoid_f(float x) {
    return 1.0f / (1.0f + __expf(-x));
}
static __device__ __forceinline__ float tanh_f(float x) {
    x = fminf(10.0f, fmaxf(-10.0f, x));
    float e = __expf(2.0f * x);
    return (e - 1.0f) / (e + 1.0f);
}
static __device__ __forceinline__ short8 xfrag(const float* xr) {
    float4 a0 = *(const float4*)xr;
    float4 a1 = *(const float4*)(xr + 4);
    short8 ax;
    ax[0] = (short)f2bf(a0.x); ax[1] = (short)f2bf(a0.y);
    ax[2] = (short)f2bf(a0.z); ax[3] = (short)f2bf(a0.w);
    ax[4] = (short)f2bf(a1.x); ax[5] = (short)f2bf(a1.y);
    ax[6] = (short)f2bf(a1.z); ax[7] = (short)f2bf(a1.w);
    return ax;
}
#define MFMA16(a, b, c) __builtin_amdgcn_mfma_f32_16x16x32_bf16((a), (b), (c), 0, 0, 0)

// =====================================================================
// NEW: quadrant-partitioned LSTM with precomputed x-projections.
// grid 256 x 256. Block (q = blk>>6, c = blk&63): batch rows [16q,16q+16),
// hidden units [16c,16c+16). Columns ordered hidden-major: col = u*4 + gate,
// so each wave (one 16-col MFMA tile) owns 4 hidden units x all 4 gates ->
// pointwise is wave-private (no barriers in the recurrent loop).
// Phase A: bulk GEMM  pre[t] = x_t*Wx + b  (K split across 4 waves, LDS reduce).
// Phase B: recurrent loop; per wave: 32 h-frag loads + 32 MFMA + 1-cell pointwise.
// =====================================================================
__global__ void __launch_bounds__(256, 1) lstm_quad(
    const float* __restrict__ X,
    const float* __restrict__ Wf, const float* __restrict__ Wi,
    const float* __restrict__ Wg, const float* __restrict__ Wo,
    const float* __restrict__ bfp, const float* __restrict__ bip,
    const float* __restrict__ bgp, const float* __restrict__ bop,
    float* __restrict__ out,       // outputs(SEQ,B,DH) ++ h_n(B,DH) ++ c_n(B,DH)
    u16*   __restrict__ pre,       // [t][blk][w][lane][4] bf16 preacts (x*Wx + b)
    u16*   __restrict__ hbuf,      // [t][b][DH] bf16, t in [0,SEQ-2]
    u32*   __restrict__ cnt)       // 32 counters at (q*8+g)*16, 64 B apart
{
    __shared__ __align__(16) u16   WB[32 * 4 * 64 * 8];   // 128 KiB B-frags [kk][ct][lane][8]
    __shared__ __align__(16) float Red[4][16][68];        // 17 KiB; 272-B rows (16B-aligned)
    __shared__ unsigned pub;

    const int tid  = threadIdx.x;
    const int blk  = blockIdx.x;
    const int q    = blk >> 6;          // quadrant: batch rows [16q, 16q+16)
    const int c    = blk & 63;          // hidden group: units [16c, 16c+16)
    const int r0   = q * 16;
    const int lane = tid & 63;
    const int w    = tid >> 6;          // wave id = column tile (16 cols)
    const int kq   = lane >> 4;
    const int cl16 = lane & 15;
    const int prow = lane >> 2;         // pointwise: batch row within tile
    const int uu   = lane & 3;          // pointwise: hidden unit within wave

    if (tid == 0) pub = 0u;

    // ---- fill WB with Wx fragments (koff = 0) ----
    // frag element (kk,ct,lf,j): k = kk*32+(lf>>4)*8+j ; block col cb = ct*16+(lf&15);
    // hidden u = cb>>2, gate = cb&3 (hidden-major column order).
    for (int i = tid; i < 32*4*64*8; i += 256) {
        int j = i & 7, lf = (i >> 3) & 63, ct = (i >> 9) & 3, kk = i >> 11;
        int k  = kk * 32 + (lf >> 4) * 8 + j;
        int cbl = ct * 16 + (lf & 15);
        int u  = cbl >> 2, g = cbl & 3;
        const float* Wp = g == 0 ? Wf : g == 1 ? Wi : g == 2 ? Wg : Wo;
        WB[i] = f2bf(Wp[(size_t)(c*16 + u) * (DIN + DH) + k]);
    }

    // bias for this lane's output column
    const int cb = w * 16 + cl16;
    const int ub = cb >> 2, gb = cb & 3;
    const float bias = (gb == 0 ? bfp : gb == 1 ? bip : gb == 2 ? bgp : bop)[c*16 + ub];

    const short8* WBF = (const short8*)WB;
    __syncthreads();

    // ================= PHASE A: pre[t] = x_t * Wx + b =================
    // K split across waves (wave w: kk in [8w, 8w+8)), LDS reduction of 4 partials.
    for (int t = 0; t < SEQ; ++t) {
        const float* xr = X + ((size_t)t * BATCH + r0 + cl16) * DIN + kq * 8;
        floatx4 a0 = {0.f,0.f,0.f,0.f}, a1 = {0.f,0.f,0.f,0.f};
        floatx4 a2 = {0.f,0.f,0.f,0.f}, a3 = {0.f,0.f,0.f,0.f};
        #pragma unroll
        for (int k8 = 0; k8 < 8; ++k8) {
            const int kk = w * 8 + k8;
            short8 xa = xfrag(xr + kk * 32);
            a0 = MFMA16(xa, WBF[(kk*4 + 0)*64 + lane], a0);
            a1 = MFMA16(xa, WBF[(kk*4 + 1)*64 + lane], a1);
            a2 = MFMA16(xa, WBF[(kk*4 + 2)*64 + lane], a2);
            a3 = MFMA16(xa, WBF[(kk*4 + 3)*64 + lane], a3);
        }
        #pragma unroll
        for (int qq = 0; qq < 4; ++qq) {
            Red[w][kq*4 + qq][ 0 + cl16] = a0[qq];
            Red[w][kq*4 + qq][16 + cl16] = a1[qq];
            Red[w][kq*4 + qq][32 + cl16] = a2[qq];
            Red[w][kq*4 + qq][48 + cl16] = a3[qq];
        }
        __syncthreads();
        float vq[4];
        #pragma unroll
        for (int qq = 0; qq < 4; ++qq)
            vq[qq] = Red[0][kq*4+qq][cb] + Red[1][kq*4+qq][cb]
                   + Red[2][kq*4+qq][cb] + Red[3][kq*4+qq][cb] + bias;
        uint2v pv;
        pv[0] = (u32)f2bf(vq[0]) | ((u32)f2bf(vq[1]) << 16);
        pv[1] = (u32)f2bf(vq[2]) | ((u32)f2bf(vq[3]) << 16);
        *(uint2v*)(pre + ((((size_t)t * 256 + blk) * 4 + w) * 64 + lane) * 4) = pv;
        __syncthreads();
    }

    // ---- refill WB with Wh fragments (koff = DIN) ----
    for (int i = tid; i < 32*4*64*8; i += 256) {
        int j = i & 7, lf = (i >> 3) & 63, ct = (i >> 9) & 3, kk = i >> 11;
        int k  = kk * 32 + (lf >> 4) * 8 + j;
        int cbl = ct * 16 + (lf & 15);
        int u  = cbl >> 2, g = cbl & 3;
        const float* Wp = g == 0 ? Wf : g == 1 ? Wi : g == 2 ? Wg : Wo;
        WB[i] = f2bf(Wp[(size_t)(c*16 + u) * (DIN + DH) + DIN + k]);
    }
    __syncthreads();

    // ================= PHASE B: recurrent loop =================
    u32* myCnt = cnt + ((q << 3) + (c >> 3)) * 16;
    volatile unsigned* pubv = &pub;
    float cstate = 0.f;
    uint2v preReg = *(const uint2v*)(pre + (((size_t)blk * 4 + w) * 64 + lane) * 4);

    for (int t = 0; t < SEQ; ++t) {
        floatx4 acc0 = { bf2f((u16)(preReg[0] & 0xffffu)),
                         bf2f((u16)(preReg[0] >> 16)),
                         bf2f((u16)(preReg[1] & 0xffffu)),
                         bf2f((u16)(preReg[1] >> 16)) };
        floatx4 acc1 = {0.f, 0.f, 0.f, 0.f};

        if (t > 0) {
            const u16* hb = hbuf + (size_t)(t-1)*(BATCH*DH) + (size_t)(r0 + cl16)*DH + kq*8;
            const unsigned target = (unsigned)t * 32u;   // 8 blocks x 4 waves per group
            unsigned avail = 0u, lastPub = 0u;
            auto pollAvail = [&]() -> unsigned {
                unsigned av;
                if (w == 0) {
                    // one 8-lane gather = all 8 quadrant counters in one round trip
                    unsigned cv = target;
                    if (lane < 8)
                        cv = __hip_atomic_load(&cnt[((q << 3) + lane) * 16],
                                               __ATOMIC_RELAXED, __HIP_MEMORY_SCOPE_AGENT);
                    av = (unsigned)__ballot(cv >= target) & 0xffu;
                    if (av != lastPub) { *pubv = ((unsigned)t << 16) | av; lastPub = av; }
                } else {
                    unsigned f = *pubv;          // waves 1-3: LDS spin, monotone encoding
                    unsigned ft = f >> 16;
                    av = (ft > (unsigned)t) ? 0xffu
                       : ((ft == (unsigned)t) ? (f & 0xffffu) : 0u);
                }
                return av;
            };
            #define WAITG(g) \
                while (!((avail >> (g)) & 1u)) { \
                    avail = pollAvail(); \
                    if (!((avail >> (g)) & 1u)) __builtin_amdgcn_s_sleep(1); \
                } \
                asm volatile("" ::: "memory");
            #define LOADG(g) \
                short8 hA##g = *(const short8*)(hb + (4*(g)+0)*32); \
                short8 hB##g = *(const short8*)(hb + (4*(g)+1)*32); \
                short8 hC##g = *(const short8*)(hb + (4*(g)+2)*32); \
                short8 hD##g = *(const short8*)(hb + (4*(g)+3)*32);
            #define MFMAG(g) \
                acc0 = MFMA16(hA##g, WBF[((4*(g)+0)*4 + w)*64 + lane], acc0); \
                acc1 = MFMA16(hB##g, WBF[((4*(g)+1)*4 + w)*64 + lane], acc1); \
                acc0 = MFMA16(hC##g, WBF[((4*(g)+2)*4 + w)*64 + lane], acc0); \
                acc1 = MFMA16(hD##g, WBF[((4*(g)+3)*4 + w)*64 + lane], acc1);
            WAITG(0) LOADG(0) WAITG(1) LOADG(1) WAITG(2) LOADG(2) WAITG(3) LOADG(3)
            WAITG(4) LOADG(4) WAITG(5) LOADG(5) WAITG(6) LOADG(6) WAITG(7) LOADG(7)
            MFMAG(0) MFMAG(1) MFMAG(2) MFMAG(3) MFMAG(4) MFMAG(5) MFMAG(6) MFMAG(7)
            #undef WAITG
            #undef LOADG
            #undef MFMAG
        }
        floatx4 acc = acc0 + acc1;

        // wave-private transpose: C/D (row = kq*4+qq, col = cl16) -> per-cell f,i,g,o
        #pragma unroll
        for (int qq = 0; qq < 4; ++qq)
            Red[w][kq*4 + qq][cl16] = acc[qq];
        asm volatile("s_waitcnt lgkmcnt(0)" ::: "memory");
        float4 gv = *(const float4*)&Red[w][prow][uu * 4];   // f,i,g,o (16B-aligned)

        float F  = sigmoid_f(gv.x);
        float I  = sigmoid_f(gv.y);
        float Gg = tanh_f(gv.z);
        float O  = sigmoid_f(gv.w);
        cstate = F * cstate + I * Gg;
        float hv = O * tanh_f(cstate);
        const int b   = r0 + prow;
        const int hid = c * 16 + w * 4 + uu;
        out[(size_t)t * (BATCH*DH) + (size_t)b * DH + hid] = hv;

        if (t < SEQ - 1) {
            u16* hd = hbuf + (size_t)t * (BATCH*DH) + (size_t)b * DH + hid;
            u32 hb16 = (u32)f2bf(hv);
            asm volatile("global_store_short %0, %1, off sc0 sc1"
                         :: "v"(hd), "v"(hb16) : "memory");
            asm volatile("s_waitcnt vmcnt(0)" ::: "memory");
            if (lane == 0)
                (void)__hip_atomic_fetch_add(myCnt, 1u, __ATOMIC_RELAXED,
                                             __HIP_MEMORY_SCOPE_AGENT);
            // prefetch next step's preacts (own block's data, lands during poll)
            preReg = *(const uint2v*)(pre + ((((size_t)(t+1) * 256 + blk) * 4 + w) * 64 + lane) * 4);
        } else {
            out[(size_t)SEQ*(BATCH*DH) + (size_t)b*DH + hid] = hv;
            out[(size_t)SEQ*(BATCH*DH) + (BATCH*DH) + (size_t)b*DH + hid] = cstate;
        }
    }
}

// =====================================================================
// FALLBACK (small workspace): round-1 kernel, verbatim. Verified passing.
// =====================================================================
template <int HIST>
__global__ void __launch_bounds__(256, 1) lstm_persist(
    const float* __restrict__ X,
    const float* __restrict__ Wf, const float* __restrict__ Wi,
    const float* __restrict__ Wg, const float* __restrict__ Wo,
    const float* __restrict__ bfp, const float* __restrict__ bip,
    const float* __restrict__ bgp, const float* __restrict__ bop,
    float* __restrict__ out,
    u16*   __restrict__ hbuf,
    unsigned* __restrict__ cnt)
{
    __shared__ __align__(16) u16 Wx_l[32 * 2 * 64 * 8];
    __shared__ __align__(16) u16 Wh_l[32 * 2 * 64 * 8];
    __shared__ __align__(16) float G[4][16][34];
    __shared__ unsigned pub;

    const int tid = threadIdx.x;
    const int blk = blockIdx.x;
    const int j0  = blk * 8;

    if (tid == 0) pub = 0u;

    for (int i = tid; i < 32 * 2 * 64 * 8; i += 256) {
        int j = i & 7, lane_f = (i >> 3) & 63, ct = (i >> 9) & 1, kk = i >> 10;
        int n = lane_f & 15, kqf = lane_f >> 4;
        int k = kk * 32 + kqf * 8 + j;
        int cc2 = ct * 16 + n;
        int gate = cc2 >> 3, jj = cc2 & 7;
        const float* Wp = gate == 0 ? Wf : gate == 1 ? Wi : gate == 2 ? Wg : Wo;
        const float* row = Wp + (size_t)(j0 + jj) * (DIN + DH);
        Wx_l[i] = f2bf(row[k]);
        Wh_l[i] = f2bf(row[DIN + k]);
    }
    __syncthreads();

    const int lane = tid & 63;
    const int w    = tid >> 6;
    const int kq   = lane >> 4;
    const int cc   = lane & 15;
    const int row_glob = w * 16 + cc;

    const float bv0 = ((cc >> 3) ? bip : bfp)[j0 + (cc & 7)];
    const float bv1 = ((cc >> 3) ? bop : bgp)[j0 + (cc & 7)];
    const floatx4 binit0 = {bv0, bv0, bv0, bv0};
    const floatx4 binit1 = {bv1, bv1, bv1, bv1};

    const short8* WxF = (const short8*)Wx_l;
    const short8* WhF = (const short8*)Wh_l;
    unsigned* myCnt = cnt + (blk >> 3) * 16;
    volatile unsigned* pubv = &pub;

    const int pr = lane >> 2, jp = lane & 3;
    float cs0 = 0.f, cs1 = 0.f;

    floatx4 x0 = binit0, x1 = binit1;
    {
        const float* xr = X + (size_t)row_glob * DIN + kq * 8;
        #pragma unroll 4
        for (int kk = 0; kk < 32; ++kk) {
            short8 ax = xfrag(xr + kk * 32);
            x0 = MFMA16(ax, WxF[(kk * 2 + 0) * 64 + lane], x0);
            x1 = MFMA16(ax, WxF[(kk * 2 + 1) * 64 + lane], x1);
        }
    }

    for (int t = 0; t < SEQ; ++t) {
        floatx4 A0 = x0, A1 = x1;

        if (t > 0) {
            const u16* hb = hbuf + (size_t)(HIST ? (t - 1) : ((t - 1) & 1)) * (BATCH * DH)
                            + (size_t)row_glob * DH + kq * 8;
            const unsigned target = (unsigned)t * 32u;
            unsigned avail = 0u, lastPub = 0u;
            auto pollAvail = [&]() -> unsigned {
                unsigned av;
                if (w == 0) {
                    unsigned cv = target;
                    if (lane < 16)
                        cv = __hip_atomic_load(&cnt[lane * 16],
                                HIST ? __ATOMIC_RELAXED : __ATOMIC_ACQUIRE,
                                __HIP_MEMORY_SCOPE_AGENT);
                    av = (unsigned)__ballot(cv >= target) & 0xFFFFu;
                    if (av != lastPub) { *pubv = ((unsigned)t << 16) | av; lastPub = av; }
                } else {
                    unsigned f = *pubv;
                    unsigned ft = f >> 16;
                    av = (ft > (unsigned)t) ? 0xFFFFu
                       : ((ft == (unsigned)t) ? (f & 0xFFFFu) : 0u);
                }
                return av;
            };
            #define WAITG(g) \
                while (!((avail >> (g)) & 1u)) { \
                    avail = pollAvail(); \
                    if (!((avail >> (g)) & 1u)) __builtin_amdgcn_s_sleep(1); \
                } \
                asm volatile("" ::: "memory");
            #define LOADG(g) \
                short8 aA##g = *(const short8*)(hb + (2 * (g)) * 32); \
                short8 aB##g = *(const short8*)(hb + (2 * (g) + 1) * 32);
            #define MFMAG(g) \
                A0 = MFMA16(aA##g, WhF[(4 * (g) + 0) * 64 + lane], A0); \
                A1 = MFMA16(aA##g, WhF[(4 * (g) + 1) * 64 + lane], A1); \
                A0 = MFMA16(aB##g, WhF[(4 * (g) + 2) * 64 + lane], A0); \
                A1 = MFMA16(aB##g, WhF[(4 * (g) + 3) * 64 + lane], A1);
            WAITG(0)  LOADG(0)  WAITG(1)  LOADG(1)  WAITG(2)  LOADG(2)  WAITG(3)  LOADG(3)
            WAITG(4)  LOADG(4)  WAITG(5)  LOADG(5)  WAITG(6)  LOADG(6)  WAITG(7)  LOADG(7)
            WAITG(8)  LOADG(8)  WAITG(9)  LOADG(9)  WAITG(10) LOADG(10) WAITG(11) LOADG(11)
            WAITG(12) LOADG(12) WAITG(13) LOADG(13) WAITG(14) LOADG(14) WAITG(15) LOADG(15)
            MFMAG(0)  MFMAG(1)  MFMAG(2)  MFMAG(3)  MFMAG(4)  MFMAG(5)  MFMAG(6)  MFMAG(7)
            MFMAG(8)  MFMAG(9)  MFMAG(10) MFMAG(11) MFMAG(12) MFMAG(13) MFMAG(14) MFMAG(15)
            #undef WAITG
            #undef LOADG
            #undef MFMAG
        }

        #pragma unroll
        for (int qq = 0; qq < 4; ++qq) {
            G[w][kq * 4 + qq][cc]      = A0[qq];
            G[w][kq * 4 + qq][16 + cc] = A1[qq];
        }
        asm volatile("s_waitcnt lgkmcnt(0)" ::: "memory");

        const float* Gr = &G[w][pr][0];
        float2 vF  = *(const float2*)(Gr + 2 * jp);
        float2 vI  = *(const float2*)(Gr + 8  + 2 * jp);
        float2 vGg = *(const float2*)(Gr + 16 + 2 * jp);
        float2 vO  = *(const float2*)(Gr + 24 + 2 * jp);
        float F0 = sigmoid_f(vF.x),  F1 = sigmoid_f(vF.y);
        float I0 = sigmoid_f(vI.x),  I1 = sigmoid_f(vI.y);
        float g0 = tanh_f(vGg.x),    g1 = tanh_f(vGg.y);
        float O0 = sigmoid_f(vO.x),  O1 = sigmoid_f(vO.y);
        cs0 = F0 * cs0 + I0 * g0;
        cs1 = F1 * cs1 + I1 * g1;
        float hv0 = O0 * tanh_f(cs0);
        float hv1 = O1 * tanh_f(cs1);
        const int b = w * 16 + pr;
        float2 ho; ho.x = hv0; ho.y = hv1;
        float* outp = out + (size_t)t * (BATCH * DH) + (size_t)b * DH + j0 + 2 * jp;

        if (t < SEQ - 1) {
            u16* dst = hbuf + (size_t)(HIST ? t : (t & 1)) * (BATCH * DH)
                       + (size_t)b * DH + j0 + 2 * jp;
            unsigned hvp = (unsigned)f2bf(hv0) | ((unsigned)f2bf(hv1) << 16);
            if (HIST) {
                asm volatile("global_store_dword %0, %1, off sc0 sc1"
                             :: "v"(dst), "v"(hvp) : "memory");
                *(float2*)outp = ho;
                asm volatile("s_waitcnt vmcnt(1)" ::: "memory");
                if (lane == 0)
                    (void)__hip_atomic_fetch_add(myCnt, 1u, __ATOMIC_RELAXED,
                                                 __HIP_MEMORY_SCOPE_AGENT);
            } else {
                *(unsigned*)dst = hvp;
                *(float2*)outp = ho;
                asm volatile("s_waitcnt vmcnt(0)" ::: "memory");
                if (lane == 0)
                    (void)__hip_atomic_fetch_add(myCnt, 1u, __ATOMIC_RELEASE,
                                                 __HIP_MEMORY_SCOPE_AGENT);
            }
            x0 = binit0; x1 = binit1;
            const float* xr = X + ((size_t)(t + 1) * BATCH + row_glob) * DIN + kq * 8;
            #pragma unroll 4
            for (int kk = 0; kk < 32; ++kk) {
                short8 ax = xfrag(xr + kk * 32);
                x0 = MFMA16(ax, WxF[(kk * 2 + 0) * 64 + lane], x0);
                x1 = MFMA16(ax, WxF[(kk * 2 + 1) * 64 + lane], x1);
            }
        } else {
            *(float2*)outp = ho;
            *(float2*)(out + (size_t)SEQ * (BATCH * DH) + (size_t)b * DH + j0 + 2 * jp) = ho;
            float2 co; co.x = cs0; co.y = cs1;
            *(float2*)(out + (size_t)SEQ * (BATCH * DH) + (BATCH * DH)
                       + (size_t)b * DH + j0 + 2 * jp) = co;
        }
    }
}

extern "C" void kernel_launch(void* const* d_in, const int* in_sizes, int n_in,
                              void* d_out, int out_size, void* d_ws, size_t ws_size,
                              hipStream_t stream) {
    (void)in_sizes; (void)n_in; (void)out_size;
    const float* X   = (const float*)d_in[0];
    const float* Wf  = (const float*)d_in[1];
    const float* bfv = (const float*)d_in[2];
    const float* Wi  = (const float*)d_in[3];
    const float* biv = (const float*)d_in[4];
    const float* Wg  = (const float*)d_in[5];
    const float* bgv = (const float*)d_in[6];
    const float* Wo  = (const float*)d_in[7];
    const float* bov = (const float*)d_in[8];
    float* out = (float*)d_out;

    unsigned char* ws = (unsigned char*)d_ws;
    u32* cnt = (u32*)ws;
    hipMemsetAsync(ws, 0, 4096, stream);

    const size_t pre_bytes  = (size_t)SEQ * BATCH * 4 * DH * 2;        // 256 MiB
    const size_t hbuf_bytes = (size_t)(SEQ - 1) * BATCH * DH * 2;      // ~64 MiB
    const size_t need_new   = 4096 + pre_bytes + hbuf_bytes;

    if (ws_size >= need_new) {
        u16* pre  = (u16*)(ws + 4096);
        u16* hbuf = (u16*)(ws + 4096 + pre_bytes);
        lstm_quad<<<256, 256, 0, stream>>>(
            X, Wf, Wi, Wg, Wo, bfv, biv, bgv, bov, out, pre, hbuf, cnt);
    } else {
        u16* hbuf = (u16*)(ws + 4096);
        const size_t need_hist = 4096 + (size_t)SEQ * BATCH * DH * 2;
        if (ws_size >= need_hist) {
            lstm_persist<1><<<128, 256, 0, stream>>>(
                X, Wf, Wi, Wg, Wo, bfv, biv, bgv, bov, out, hbuf, (unsigned*)cnt);
        } else {
            lstm_persist<0><<<128, 256, 0, stream>>>(
                X, Wf, Wi, Wg, Wo, bfv, biv, bgv, bov, out, hbuf, (unsigned*)cnt);
        }
    }
}

// Round 3
// 4214.136 us; speedup vs baseline: 1.7384x; 1.7384x over previous
//
#include <hip/hip_runtime.h>

// Problem constants
#define SEQ   512
#define BATCH 64
#define DIN   1024
#define DH    1024

typedef unsigned short u16;
typedef unsigned int   u32;
typedef __attribute__((ext_vector_type(8))) short  short8;   // 8 x bf16 MFMA operand
typedef __attribute__((ext_vector_type(4))) float  floatx4;  // MFMA accumulator
typedef __attribute__((ext_vector_type(2))) unsigned int uint2v;
typedef __attribute__((ext_vector_type(4))) unsigned int uint4v;

static __device__ __forceinline__ u16 f2bf(float f) {
    union { float f; unsigned u; } v; v.f = f;
    unsigned r = v.u + 0x7fffu + ((v.u >> 16) & 1u);   // RNE
    return (u16)(r >> 16);
}
static __device__ __forceinline__ float bf2f(u16 x) {
    union { u32 u; float f; } v; v.u = ((u32)x) << 16; return v.f;
}
static __device__ __forceinline__ float sigmoid_f(float x) {
    return 1.0f / (1.0f + __expf(-x));
}
static __device__ __forceinline__ float tanh_f(float x) {
    x = fminf(10.0f, fmaxf(-10.0f, x));
    float e = __expf(2.0f * x);
    return (e - 1.0f) / (e + 1.0f);
}
static __device__ __forceinline__ short8 xfrag(const float* xr) {
    float4 a0 = *(const float4*)xr;
    float4 a1 = *(const float4*)(xr + 4);
    short8 ax;
    ax[0] = (short)f2bf(a0.x); ax[1] = (short)f2bf(a0.y);
    ax[2] = (short)f2bf(a0.z); ax[3] = (short)f2bf(a0.w);
    ax[4] = (short)f2bf(a1.x); ax[5] = (short)f2bf(a1.y);
    ax[6] = (short)f2bf(a1.z); ax[7] = (short)f2bf(a1.w);
    return ax;
}
#define MFMA16(a, b, c) __builtin_amdgcn_mfma_f32_16x16x32_bf16((a), (b), (c), 0, 0, 0)

// =====================================================================
// v3: flag-based sync (no atomics), Wh in registers, packed h stores,
// barrier-free Phase A on pre-converted bf16 X.
// grid 256. block (q=blk>>6, c=blk&63): batch rows [16q,16q+16), hidden
// units [16c,16c+16). Hidden-major column order (col = u*4+gate) so each
// wave owns 4 hidden units x 4 gates -> wave-private pointwise.
// flags[q*64+c]: 1 = phase0 done; t+2 = h[t] stored (monotone).
// XBF=1: X pre-converted to bf16 (phase 0). XBF=0: convert on the fly.
// =====================================================================
template <int XBF>
__global__ void __launch_bounds__(256, 1) lstm_v3(
    const float* __restrict__ X,
    const float* __restrict__ Wf, const float* __restrict__ Wi,
    const float* __restrict__ Wg, const float* __restrict__ Wo,
    const float* __restrict__ bfp, const float* __restrict__ bip,
    const float* __restrict__ bgp, const float* __restrict__ bop,
    float* __restrict__ out,       // outputs(SEQ,B,DH) ++ h_n(B,DH) ++ c_n(B,DH)
    u16*   __restrict__ X16,       // [t][b][k] bf16 (XBF=1 only)
    u16*   __restrict__ pre,       // [t][blk][ct][lane][4] bf16 preacts (x*Wx + b)
    u16*   __restrict__ hbuf,      // [t][b][DH] bf16
    u32*   __restrict__ flags)     // 256 flags, contiguous per quadrant
{
    __shared__ __align__(16) u16   WB[32 * 4 * 64 * 8];   // 128 KiB B-frags [kk][ct][lane][8]
    __shared__ __align__(16) float Red[4][16][20];        // wave-private gate transpose

    const int tid  = threadIdx.x;
    const int blk  = blockIdx.x;
    const int q    = blk >> 6;
    const int c    = blk & 63;
    const int r0   = q * 16;
    const int lane = tid & 63;
    const int w    = tid >> 6;
    const int kq   = lane >> 4;
    const int cl16 = lane & 15;
    const int prow = lane >> 2;
    const int uu   = lane & 3;
    const size_t BD = (size_t)BATCH * DH;

    // ---------------- Phase 0: X fp32 -> bf16 (de-duplicated, WT) ----------------
    if (XBF) {
        // block converts t in [8c, 8c+8), rows [r0, r0+16), all k
        for (int i = tid; i < 8 * 16 * 128; i += 256) {   // units of 8 floats
            int k8 = i & 127, rr = (i >> 7) & 15, tt = i >> 11;
            const size_t off = ((size_t)(c * 8 + tt) * BATCH + r0 + rr) * DIN + k8 * 8;
            float4 f0 = *(const float4*)(X + off);
            float4 f1 = *(const float4*)(X + off + 4);
            uint4v pk;
            pk[0] = (u32)f2bf(f0.x) | ((u32)f2bf(f0.y) << 16);
            pk[1] = (u32)f2bf(f0.z) | ((u32)f2bf(f0.w) << 16);
            pk[2] = (u32)f2bf(f1.x) | ((u32)f2bf(f1.y) << 16);
            pk[3] = (u32)f2bf(f1.z) | ((u32)f2bf(f1.w) << 16);
            asm volatile("global_store_dwordx4 %0, %1, off sc0 sc1"
                         :: "v"(X16 + off), "v"(pk) : "memory");
        }
        asm volatile("s_waitcnt vmcnt(0)" ::: "memory");
        __syncthreads();
        if (tid == 0) {
            u32 one = 1u;
            asm volatile("global_store_dword %0, %1, off sc0 sc1"
                         :: "v"(&flags[(q << 6) + c]), "v"(one) : "memory");
        }
    }

    // ---------------- W fragment fill (lambda, koff selects Wx/Wh) ----------------
    auto fillWB = [&](int koff) {
        for (int i = tid; i < 32 * 4 * 64 * 8; i += 256) {
            int j = i & 7, lf = (i >> 3) & 63, ct = (i >> 9) & 3, kk = i >> 11;
            int k   = kk * 32 + (lf >> 4) * 8 + j;
            int cbl = ct * 16 + (lf & 15);
            int u = cbl >> 2, g = cbl & 3;
            const float* Wp = g == 0 ? Wf : g == 1 ? Wi : g == 2 ? Wg : Wo;
            WB[i] = f2bf(Wp[(size_t)(c * 16 + u) * (DIN + DH) + koff + k]);
        }
    };
    const short8* WBF = (const short8*)WB;

    fillWB(0);                 // Wx (overlaps other blocks' phase 0)
    __syncthreads();

    // bias per ct (column = ct*16 + cl16)
    float bC[4];
    #pragma unroll
    for (int ct = 0; ct < 4; ++ct) {
        int col = ct * 16 + cl16;
        int u = col >> 2, g = col & 3;
        bC[ct] = (g == 0 ? bfp : g == 1 ? bip : g == 2 ? bgp : bop)[c * 16 + u];
    }

    // wait for own quadrant's phase 0 (one 64-lane load per poll)
    if (XBF) {
        for (;;) {
            u32 fv = __hip_atomic_load(&flags[(q << 6) + lane],
                                       __ATOMIC_RELAXED, __HIP_MEMORY_SCOPE_AGENT);
            if (__ballot(fv >= 1u) == ~0ull) break;
            __builtin_amdgcn_s_sleep(1);
        }
        asm volatile("" ::: "memory");
    }

    // ---------------- Phase A: pre[t] = x_t*Wx + b, 4 t's per wave ----------------
    for (int tb = 0; tb < 32; ++tb) {
        const int tA = tb * 16 + w * 4;
        floatx4 acc[4][4];
        #pragma unroll
        for (int tt = 0; tt < 4; ++tt)
            #pragma unroll
            for (int ct = 0; ct < 4; ++ct)
                acc[tt][ct] = (floatx4){bC[ct], bC[ct], bC[ct], bC[ct]};
        #pragma unroll 2
        for (int kk = 0; kk < 32; ++kk) {
            short8 B0 = WBF[(kk * 4 + 0) * 64 + lane];
            short8 B1 = WBF[(kk * 4 + 1) * 64 + lane];
            short8 B2 = WBF[(kk * 4 + 2) * 64 + lane];
            short8 B3 = WBF[(kk * 4 + 3) * 64 + lane];
            #pragma unroll
            for (int tt = 0; tt < 4; ++tt) {
                short8 a;
                if (XBF) a = *(const short8*)(X16 + ((size_t)(tA + tt) * BATCH + r0 + cl16) * DIN
                                              + kk * 32 + kq * 8);
                else     a = xfrag(X + ((size_t)(tA + tt) * BATCH + r0 + cl16) * DIN
                                   + kk * 32 + kq * 8);
                acc[tt][0] = MFMA16(a, B0, acc[tt][0]);
                acc[tt][1] = MFMA16(a, B1, acc[tt][1]);
                acc[tt][2] = MFMA16(a, B2, acc[tt][2]);
                acc[tt][3] = MFMA16(a, B3, acc[tt][3]);
            }
        }
        #pragma unroll
        for (int tt = 0; tt < 4; ++tt)
            #pragma unroll
            for (int ct = 0; ct < 4; ++ct) {
                uint2v pv;
                pv[0] = (u32)f2bf(acc[tt][ct][0]) | ((u32)f2bf(acc[tt][ct][1]) << 16);
                pv[1] = (u32)f2bf(acc[tt][ct][2]) | ((u32)f2bf(acc[tt][ct][3]) << 16);
                *(uint2v*)(pre + ((((size_t)(tA + tt) * 256 + blk) * 4 + ct) << 8) + (lane << 2)) = pv;
            }
    }

    // ---------------- Wh -> registers (32 frags, ct = w column) ----------------
    __syncthreads();           // all waves done reading Wx from WB
    fillWB(DIN);
    __syncthreads();

    short8 WH0,  WH1,  WH2,  WH3,  WH4,  WH5,  WH6,  WH7;
    short8 WH8,  WH9,  WH10, WH11, WH12, WH13, WH14, WH15;
    short8 WH16, WH17, WH18, WH19, WH20, WH21, WH22, WH23;
    short8 WH24, WH25, WH26, WH27, WH28, WH29, WH30, WH31;
    #define LDWH(i) WH##i = WBF[((i) * 4 + w) * 64 + lane];
    LDWH(0)  LDWH(1)  LDWH(2)  LDWH(3)  LDWH(4)  LDWH(5)  LDWH(6)  LDWH(7)
    LDWH(8)  LDWH(9)  LDWH(10) LDWH(11) LDWH(12) LDWH(13) LDWH(14) LDWH(15)
    LDWH(16) LDWH(17) LDWH(18) LDWH(19) LDWH(20) LDWH(21) LDWH(22) LDWH(23)
    LDWH(24) LDWH(25) LDWH(26) LDWH(27) LDWH(28) LDWH(29) LDWH(30) LDWH(31)
    #undef LDWH

    // ---------------- Phase B: recurrent loop ----------------
    float cstate = 0.f;
    uint2v preReg = *(const uint2v*)(pre + (((size_t)blk * 4 + w) << 8) + (lane << 2));

    for (int t = 0; t < SEQ; ++t) {
        floatx4 cAx = { bf2f((u16)(preReg[0] & 0xffffu)), bf2f((u16)(preReg[0] >> 16)),
                        bf2f((u16)(preReg[1] & 0xffffu)), bf2f((u16)(preReg[1] >> 16)) };
        floatx4 cBx = {0.f,0.f,0.f,0.f}, cCx = {0.f,0.f,0.f,0.f}, cDx = {0.f,0.f,0.f,0.f};

        if (t > 0) {
            // single wait: all 64 quadrant flags in ONE 64-lane load + ballot
            const u32 tgt = (u32)t + 1u;
            for (;;) {
                u32 fv = __hip_atomic_load(&flags[(q << 6) + lane],
                                           __ATOMIC_RELAXED, __HIP_MEMORY_SCOPE_AGENT);
                if (__ballot(fv >= tgt) == ~0ull) break;
                __builtin_amdgcn_s_sleep(1);
            }
            asm volatile("" ::: "memory");

            const u16* hb = hbuf + (size_t)(t - 1) * BD + (size_t)(r0 + cl16) * DH + (kq << 3);
            #define LOADH(g) \
                short8 hA##g = *(const short8*)(hb + (4*(g)+0)*32); \
                short8 hB##g = *(const short8*)(hb + (4*(g)+1)*32); \
                short8 hC##g = *(const short8*)(hb + (4*(g)+2)*32); \
                short8 hD##g = *(const short8*)(hb + (4*(g)+3)*32);
            #define STEPG(g, W0_, W1_, W2_, W3_) \
                cAx = MFMA16(hA##g, W0_, cAx); \
                cBx = MFMA16(hB##g, W1_, cBx); \
                cCx = MFMA16(hC##g, W2_, cCx); \
                cDx = MFMA16(hD##g, W3_, cDx);
            LOADH(0) LOADH(1) LOADH(2) LOADH(3) LOADH(4) LOADH(5) LOADH(6) LOADH(7)
            STEPG(0, WH0,  WH1,  WH2,  WH3)
            STEPG(1, WH4,  WH5,  WH6,  WH7)
            STEPG(2, WH8,  WH9,  WH10, WH11)
            STEPG(3, WH12, WH13, WH14, WH15)
            STEPG(4, WH16, WH17, WH18, WH19)
            STEPG(5, WH20, WH21, WH22, WH23)
            STEPG(6, WH24, WH25, WH26, WH27)
            STEPG(7, WH28, WH29, WH30, WH31)
            #undef LOADH
            #undef STEPG
        }
        floatx4 acc = (cAx + cBx) + (cCx + cDx);

        // wave-private transpose: (row = kq*4+qq, col = cl16) -> per-cell f,i,g,o
        #pragma unroll
        for (int qq = 0; qq < 4; ++qq)
            Red[w][(kq << 2) + qq][cl16] = acc[qq];
        asm volatile("s_waitcnt lgkmcnt(0)" ::: "memory");
        float4 gv = *(const float4*)&Red[w][prow][uu << 2];   // f,i,g,o

        float F  = sigmoid_f(gv.x);
        float I  = sigmoid_f(gv.y);
        float Gg = tanh_f(gv.z);
        float O  = sigmoid_f(gv.w);
        cstate = F * cstate + I * Gg;
        float hv = O * tanh_f(cstate);
        const int b   = r0 + prow;
        const int hid = (c << 4) + (w << 2) + uu;

        if (t < SEQ - 1) {
            // pack 4 bf16 per row via quad-swizzle -> one 8B WT store per row
            u32 b16 = (u32)f2bf(hv);
            u32 s1  = (u32)__builtin_amdgcn_ds_swizzle((int)b16, 0x80F5); // quads (1,1,3,3)
            u32 p   = b16 | (s1 << 16);
            u32 p2  = (u32)__builtin_amdgcn_ds_swizzle((int)p, 0x80AA);   // quads (2,2,2,2)
            if ((lane & 3) == 0) {
                u16* hd = hbuf + (size_t)t * BD + (size_t)b * DH + (c << 4) + (w << 2);
                uint2v hp; hp[0] = p; hp[1] = p2;
                asm volatile("global_store_dwordx2 %0, %1, off sc0 sc1"
                             :: "v"(hd), "v"(hp) : "memory");
            }
            asm volatile("s_waitcnt vmcnt(0)" ::: "memory");
            __syncthreads();   // all waves' h stores in LLC
            if (tid == 0) {
                u32 fv = (u32)t + 2u;
                asm volatile("global_store_dword %0, %1, off sc0 sc1"
                             :: "v"(&flags[(q << 6) + c]), "v"(fv) : "memory");
            }
            // off critical path: out store + next preacts prefetch
            out[(size_t)t * BD + (size_t)b * DH + hid] = hv;
            preReg = *(const uint2v*)(pre + ((((size_t)(t + 1) * 256 + blk) * 4 + w) << 8) + (lane << 2));
        } else {
            out[(size_t)t * BD + (size_t)b * DH + hid] = hv;
            out[(size_t)SEQ * BD + (size_t)b * DH + hid] = hv;
            out[(size_t)SEQ * BD + BD + (size_t)b * DH + hid] = cstate;
        }
    }
}

// =====================================================================
// FALLBACK (small workspace): round-1 kernel, verbatim. Verified passing.
// =====================================================================
template <int HIST>
__global__ void __launch_bounds__(256, 1) lstm_persist(
    const float* __restrict__ X,
    const float* __restrict__ Wf, const float* __restrict__ Wi,
    const float* __restrict__ Wg, const float* __restrict__ Wo,
    const float* __restrict__ bfp, const float* __restrict__ bip,
    const float* __restrict__ bgp, const float* __restrict__ bop,
    float* __restrict__ out,
    u16*   __restrict__ hbuf,
    unsigned* __restrict__ cnt)
{
    __shared__ __align__(16) u16 Wx_l[32 * 2 * 64 * 8];
    __shared__ __align__(16) u16 Wh_l[32 * 2 * 64 * 8];
    __shared__ __align__(16) float G[4][16][34];
    __shared__ unsigned pub;

    const int tid = threadIdx.x;
    const int blk = blockIdx.x;
    const int j0  = blk * 8;

    if (tid == 0) pub = 0u;

    for (int i = tid; i < 32 * 2 * 64 * 8; i += 256) {
        int j = i & 7, lane_f = (i >> 3) & 63, ct = (i >> 9) & 1, kk = i >> 10;
        int n = lane_f & 15, kqf = lane_f >> 4;
        int k = kk * 32 + kqf * 8 + j;
        int cc2 = ct * 16 + n;
        int gate = cc2 >> 3, jj = cc2 & 7;
        const float* Wp = gate == 0 ? Wf : gate == 1 ? Wi : gate == 2 ? Wg : Wo;
        const float* row = Wp + (size_t)(j0 + jj) * (DIN + DH);
        Wx_l[i] = f2bf(row[k]);
        Wh_l[i] = f2bf(row[DIN + k]);
    }
    __syncthreads();

    const int lane = tid & 63;
    const int w    = tid >> 6;
    const int kq   = lane >> 4;
    const int cc   = lane & 15;
    const int row_glob = w * 16 + cc;

    const float bv0 = ((cc >> 3) ? bip : bfp)[j0 + (cc & 7)];
    const float bv1 = ((cc >> 3) ? bop : bgp)[j0 + (cc & 7)];
    const floatx4 binit0 = {bv0, bv0, bv0, bv0};
    const floatx4 binit1 = {bv1, bv1, bv1, bv1};

    const short8* WxF = (const short8*)Wx_l;
    const short8* WhF = (const short8*)Wh_l;
    unsigned* myCnt = cnt + (blk >> 3) * 16;
    volatile unsigned* pubv = &pub;

    const int pr = lane >> 2, jp = lane & 3;
    float cs0 = 0.f, cs1 = 0.f;

    floatx4 x0 = binit0, x1 = binit1;
    {
        const float* xr = X + (size_t)row_glob * DIN + kq * 8;
        #pragma unroll 4
        for (int kk = 0; kk < 32; ++kk) {
            short8 ax = xfrag(xr + kk * 32);
            x0 = MFMA16(ax, WxF[(kk * 2 + 0) * 64 + lane], x0);
            x1 = MFMA16(ax, WxF[(kk * 2 + 1) * 64 + lane], x1);
        }
    }

    for (int t = 0; t < SEQ; ++t) {
        floatx4 A0 = x0, A1 = x1;

        if (t > 0) {
            const u16* hb = hbuf + (size_t)(HIST ? (t - 1) : ((t - 1) & 1)) * (BATCH * DH)
                            + (size_t)row_glob * DH + kq * 8;
            const unsigned target = (unsigned)t * 32u;
            unsigned avail = 0u, lastPub = 0u;
            auto pollAvail = [&]() -> unsigned {
                unsigned av;
                if (w == 0) {
                    unsigned cv = target;
                    if (lane < 16)
                        cv = __hip_atomic_load(&cnt[lane * 16],
                                HIST ? __ATOMIC_RELAXED : __ATOMIC_ACQUIRE,
                                __HIP_MEMORY_SCOPE_AGENT);
                    av = (unsigned)__ballot(cv >= target) & 0xFFFFu;
                    if (av != lastPub) { *pubv = ((unsigned)t << 16) | av; lastPub = av; }
                } else {
                    unsigned f = *pubv;
                    unsigned ft = f >> 16;
                    av = (ft > (unsigned)t) ? 0xFFFFu
                       : ((ft == (unsigned)t) ? (f & 0xFFFFu) : 0u);
                }
                return av;
            };
            #define WAITG(g) \
                while (!((avail >> (g)) & 1u)) { \
                    avail = pollAvail(); \
                    if (!((avail >> (g)) & 1u)) __builtin_amdgcn_s_sleep(1); \
                } \
                asm volatile("" ::: "memory");
            #define LOADG(g) \
                short8 aA##g = *(const short8*)(hb + (2 * (g)) * 32); \
                short8 aB##g = *(const short8*)(hb + (2 * (g) + 1) * 32);
            #define MFMAG(g) \
                A0 = MFMA16(aA##g, WhF[(4 * (g) + 0) * 64 + lane], A0); \
                A1 = MFMA16(aA##g, WhF[(4 * (g) + 1) * 64 + lane], A1); \
                A0 = MFMA16(aB##g, WhF[(4 * (g) + 2) * 64 + lane], A0); \
                A1 = MFMA16(aB##g, WhF[(4 * (g) + 3) * 64 + lane], A1);
            WAITG(0)  LOADG(0)  WAITG(1)  LOADG(1)  WAITG(2)  LOADG(2)  WAITG(3)  LOADG(3)
            WAITG(4)  LOADG(4)  WAITG(5)  LOADG(5)  WAITG(6)  LOADG(6)  WAITG(7)  LOADG(7)
            WAITG(8)  LOADG(8)  WAITG(9)  LOADG(9)  WAITG(10) LOADG(10) WAITG(11) LOADG(11)
            WAITG(12) LOADG(12) WAITG(13) LOADG(13) WAITG(14) LOADG(14) WAITG(15) LOADG(15)
            MFMAG(0)  MFMAG(1)  MFMAG(2)  MFMAG(3)  MFMAG(4)  MFMAG(5)  MFMAG(6)  MFMAG(7)
            MFMAG(8)  MFMAG(9)  MFMAG(10) MFMAG(11) MFMAG(12) MFMAG(13) MFMAG(14) MFMAG(15)
            #undef WAITG
            #undef LOADG
            #undef MFMAG
        }

        #pragma unroll
        for (int qq = 0; qq < 4; ++qq) {
            G[w][kq * 4 + qq][cc]      = A0[qq];
            G[w][kq * 4 + qq][16 + cc] = A1[qq];
        }
        asm volatile("s_waitcnt lgkmcnt(0)" ::: "memory");

        const float* Gr = &G[w][pr][0];
        float2 vF  = *(const float2*)(Gr + 2 * jp);
        float2 vI  = *(const float2*)(Gr + 8  + 2 * jp);
        float2 vGg = *(const float2*)(Gr + 16 + 2 * jp);
        float2 vO  = *(const float2*)(Gr + 24 + 2 * jp);
        float F0 = sigmoid_f(vF.x),  F1 = sigmoid_f(vF.y);
        float I0 = sigmoid_f(vI.x),  I1 = sigmoid_f(vI.y);
        float g0 = tanh_f(vGg.x),    g1 = tanh_f(vGg.y);
        float O0 = sigmoid_f(vO.x),  O1 = sigmoid_f(vO.y);
        cs0 = F0 * cs0 + I0 * g0;
        cs1 = F1 * cs1 + I1 * g1;
        float hv0 = O0 * tanh_f(cs0);
        float hv1 = O1 * tanh_f(cs1);
        const int b = w * 16 + pr;
        float2 ho; ho.x = hv0; ho.y = hv1;
        float* outp = out + (size_t)t * (BATCH * DH) + (size_t)b * DH + j0 + 2 * jp;

        if (t < SEQ - 1) {
            u16* dst = hbuf + (size_t)(HIST ? t : (t & 1)) * (BATCH * DH)
                       + (size_t)b * DH + j0 + 2 * jp;
            unsigned hvp = (unsigned)f2bf(hv0) | ((unsigned)f2bf(hv1) << 16);
            if (HIST) {
                asm volatile("global_store_dword %0, %1, off sc0 sc1"
                             :: "v"(dst), "v"(hvp) : "memory");
                *(float2*)outp = ho;
                asm volatile("s_waitcnt vmcnt(1)" ::: "memory");
                if (lane == 0)
                    (void)__hip_atomic_fetch_add(myCnt, 1u, __ATOMIC_RELAXED,
                                                 __HIP_MEMORY_SCOPE_AGENT);
            } else {
                *(unsigned*)dst = hvp;
                *(float2*)outp = ho;
                asm volatile("s_waitcnt vmcnt(0)" ::: "memory");
                if (lane == 0)
                    (void)__hip_atomic_fetch_add(myCnt, 1u, __ATOMIC_RELEASE,
                                                 __HIP_MEMORY_SCOPE_AGENT);
            }
            x0 = binit0; x1 = binit1;
            const float* xr = X + ((size_t)(t + 1) * BATCH + row_glob) * DIN + kq * 8;
            #pragma unroll 4
            for (int kk = 0; kk < 32; ++kk) {
                short8 ax = xfrag(xr + kk * 32);
                x0 = MFMA16(ax, WxF[(kk * 2 + 0) * 64 + lane], x0);
                x1 = MFMA16(ax, WxF[(kk * 2 + 1) * 64 + lane], x1);
            }
        } else {
            *(float2*)outp = ho;
            *(float2*)(out + (size_t)SEQ * (BATCH * DH) + (size_t)b * DH + j0 + 2 * jp) = ho;
            float2 co; co.x = cs0; co.y = cs1;
            *(float2*)(out + (size_t)SEQ * (BATCH * DH) + (BATCH * DH)
                       + (size_t)b * DH + j0 + 2 * jp) = co;
        }
    }
}

extern "C" void kernel_launch(void* const* d_in, const int* in_sizes, int n_in,
                              void* d_out, int out_size, void* d_ws, size_t ws_size,
                              hipStream_t stream) {
    (void)in_sizes; (void)n_in; (void)out_size;
    const float* X   = (const float*)d_in[0];
    const float* Wf  = (const float*)d_in[1];
    const float* bfv = (const float*)d_in[2];
    const float* Wi  = (const float*)d_in[3];
    const float* biv = (const float*)d_in[4];
    const float* Wg  = (const float*)d_in[5];
    const float* bgv = (const float*)d_in[6];
    const float* Wo  = (const float*)d_in[7];
    const float* bov = (const float*)d_in[8];
    float* out = (float*)d_out;

    unsigned char* ws = (unsigned char*)d_ws;
    u32* flags = (u32*)ws;
    hipMemsetAsync(ws, 0, 4096, stream);

    const size_t x16_b = (size_t)SEQ * BATCH * DIN * 2;        //  64 MiB
    const size_t pre_b = (size_t)SEQ * BATCH * 4 * DH * 2;     // 256 MiB
    const size_t h_b   = (size_t)SEQ * BATCH * DH * 2;         //  64 MiB

    if (ws_size >= 4096 + x16_b + pre_b + h_b) {
        u16* X16  = (u16*)(ws + 4096);
        u16* pre  = (u16*)(ws + 4096 + x16_b);
        u16* hbuf = (u16*)(ws + 4096 + x16_b + pre_b);
        lstm_v3<1><<<256, 256, 0, stream>>>(
            X, Wf, Wi, Wg, Wo, bfv, biv, bgv, bov, out, X16, pre, hbuf, flags);
    } else if (ws_size >= 4096 + pre_b + h_b) {
        u16* pre  = (u16*)(ws + 4096);
        u16* hbuf = (u16*)(ws + 4096 + pre_b);
        lstm_v3<0><<<256, 256, 0, stream>>>(
            X, Wf, Wi, Wg, Wo, bfv, biv, bgv, bov, out, (u16*)nullptr, pre, hbuf, flags);
    } else if (ws_size >= 4096 + h_b) {
        u16* hbuf = (u16*)(ws + 4096);
        lstm_persist<1><<<128, 256, 0, stream>>>(
            X, Wf, Wi, Wg, Wo, bfv, biv, bgv, bov, out, hbuf, (unsigned*)flags);
    } else {
        u16* hbuf = (u16*)(ws + 4096);
        lstm_persist<0><<<128, 256, 0, stream>>>(
            X, Wf, Wi, Wg, Wo, bfv, biv, bgv, bov, out, hbuf, (unsigned*)flags);
    }
}